// Round 11
// baseline (140.729 us; speedup 1.0000x reference)
//
#include <hip/hip_runtime.h>
#include <hip/hip_bf16.h>

#define B_DIM 4096
#define M_DIM 4096
#define K_DIM 4096
#define NCODE 512

typedef __attribute__((ext_vector_type(4))) float f32x4;
typedef __attribute__((ext_vector_type(8))) short short8;

__device__ __forceinline__ unsigned short f2bf(float f) {
    union { float f; unsigned u; } c; c.f = f;
    unsigned u = c.u;
    return (unsigned short)((u + 0x7FFFu + ((u >> 16) & 1u)) >> 16);
}

// ---------------------------------------------------------------------------
// Fused prep: blocks [0,8192) dequantize codes -> bf16 W; [8192,16384) cvt A.
// ---------------------------------------------------------------------------
__global__ __launch_bounds__(256) void prep_kernel(const int* __restrict__ Q,
                                                   const float* __restrict__ cb,
                                                   short* __restrict__ Wout,
                                                   const float* __restrict__ in,
                                                   short* __restrict__ Ab) {
    const int b = blockIdx.x;
    if (b < 8192) {
        const int t = b * 256 + threadIdx.x;
        const int code = Q[t] & 0xFFFF;
        const float4* g = (const float4*)(cb + (size_t)code * 8);
        const float4 v0 = g[0];
        const float4 v1 = g[1];
        short8 o;
        o[0] = f2bf(v0.x); o[1] = f2bf(v0.y); o[2] = f2bf(v0.z); o[3] = f2bf(v0.w);
        o[4] = f2bf(v1.x); o[5] = f2bf(v1.y); o[6] = f2bf(v1.z); o[7] = f2bf(v1.w);
        *(short8*)(Wout + (size_t)t * 8) = o;
    } else {
        const int t = (b - 8192) * 256 + threadIdx.x;
        const float4* p = (const float4*)(in + (size_t)t * 8);
        const float4 v0 = p[0];
        const float4 v1 = p[1];
        short8 o;
        o[0] = f2bf(v0.x); o[1] = f2bf(v0.y); o[2] = f2bf(v0.z); o[3] = f2bf(v0.w);
        o[4] = f2bf(v1.x); o[5] = f2bf(v1.y); o[6] = f2bf(v1.z); o[7] = f2bf(v1.w);
        *(short8*)(Ab + (size_t)t * 8) = o;
    }
}

// ---------------------------------------------------------------------------
// GEMM: C[B,M] = A[B,K] * W[M,K]^T — m201-style 8-phase schedule.
// 256x256 tile, BK=64, 8 waves (2x4, wave tile 128x64), 16x16x32 MFMA,
// 2-buffer dbuf (2 x 32K shorts = 128 KB). 4 phases per K-tile, each:
//   { ds-reads (10/6/8/0) || stage 1 half-tile (2 GLD) ; barrier ;
//     lgkmcnt(0) ; setprio(1) ; 16 MFMA ; setprio(0) ; barrier }
// Stage schedule (group t): ph1 A0(t+1), ph2 A1(t+1)  [other buffer],
//                           ph3 B0(t+2), ph4 B1(t+2)  [current buffer].
// vmcnt(4) only at ph4.
// Hazard audit:
//  - visibility: tile t's loads (A@grp t-1 ph1,2; B@grp t-2 ph3,4) are the 8
//    oldest of the 12 outstanding at grp t-1 ph4 -> vmcnt(4) drains them;
//    barrier publishes; grp t's reads follow. Prologue: tile0 (8) + B0,B1(1)
//    (4) issued, vmcnt(4)+barrier covers tile 0.
//  - overwrite: A-halves of buf(t) are read at ph1 (kk0) and ph3 (kk1) of grp
//    t; re-staged (as tile t+2) at grp t+1 ph1/ph2 — after ph3's lgkm(0) and
//    >=3 barriers. B-halves of buf(t) are read at ph1/ph2 only (all four kk1
//    b-frags read at ph2); staged (tile t+2) at ph3/ph4 — barrier-separated.
//  - tail: stage indices clamp to NT-1; clamped writes land in dead or
//    identical-data regions (checked per-group above).
// LDS swizzle (BK=64 rows = 8 x 16B units): stored unit = u ^ (row&7);
// GLOBAL source inverse-swizzled (both-sides rule) -> conflict-free b128.
// ---------------------------------------------------------------------------
#define BM 256
#define BN 256
#define BK 64
#define NT (K_DIM / BK)   // 64

#define GLD(src, dst) \
    __builtin_amdgcn_global_load_lds( \
        (const __attribute__((address_space(1))) void*)(src), \
        (__attribute__((address_space(3))) void*)(dst), 16, 0, 0)

#define MFMA(a, b, c) __builtin_amdgcn_mfma_f32_16x16x32_bf16(a, b, c, 0, 0, 0)

__global__ __launch_bounds__(512, 2) void gemm_bt_kernel(const short* __restrict__ A,
                                                         const short* __restrict__ Wd,
                                                         float* __restrict__ C) {
    __shared__ short lds[2 * 32768];   // 2 bufs x (A 32KB | B 32KB) = 128 KB

    const int tid  = threadIdx.x;
    const int wave = tid >> 6;
    const int lane = tid & 63;

    // XCD-chunked swizzle: 256 blocks -> 8 XCDs, each a 4x8 block chunk
    const int bid = blockIdx.x;
    const int xcd = bid & 7;
    const int s   = bid >> 3;
    const int by  = (xcd >> 1) * 4 + (s >> 3);
    const int bx  = (xcd & 1) * 8 + (s & 7);

    const int rowBase = by * BM;
    const int colBase = bx * BN;

    const int wr = wave >> 2;                 // 0..1  (128-row half)
    const int wc = wave & 3;                  // 0..3  (64-col quarter)

    // ---- staging: thread covers rows (tid>>3)+c*64, stored unit tid&7 ----
    const int rA0 = tid >> 3;                 // 0..63
    const int uu  = (tid & 7) ^ (rA0 & 7);    // inverse-swizzled logical unit
    const int stOff = rA0 * 64 + (tid & 7) * 8;   // shorts; +c*4096
    const short* aSrcB = A  + (size_t)(rowBase + rA0) * K_DIM + uu * 8;
    const short* bSrcB = Wd + (size_t)(colBase + rA0) * K_DIM + uu * 8;

    // half h of A-tile = row blocks c in {2h, 2h+1}
#define STAGE_A(tt, h, dstbuf) { \
        const size_t ko = (size_t)(tt) * BK; \
        GLD(aSrcB + ko + (2*(h))   * (64 * K_DIM), &lds[(dstbuf) + (2*(h))   * 4096 + stOff]); \
        GLD(aSrcB + ko + (2*(h)+1) * (64 * K_DIM), &lds[(dstbuf) + (2*(h)+1) * 4096 + stOff]); }
#define STAGE_B(tt, h, dstbuf) { \
        const size_t ko = (size_t)(tt) * BK; \
        GLD(bSrcB + ko + (2*(h))   * (64 * K_DIM), &lds[(dstbuf) + 16384 + (2*(h))   * 4096 + stOff]); \
        GLD(bSrcB + ko + (2*(h)+1) * (64 * K_DIM), &lds[(dstbuf) + 16384 + (2*(h)+1) * 4096 + stOff]); }

    // ---- fragment read offsets (shorts, within a buffer) ----
    const int l15 = lane & 15;
    const int l4  = lane >> 4;
    const int uk0 = ((l4 ^ (l15 & 7))) * 8;   // kk=0 stored-unit offset
    const int uk1 = uk0 ^ 32;                 // kk=1 (unit XOR 4)
    const int aRow = (wr * 128 + l15) * 64;           // + m*1024 + ukk
    const int bRow = 16384 + (wc * 64 + l15) * 64;    // + n*1024 + ukk

    f32x4 acc[8][4] = {};

    // ---- prologue: tile0 full + B0,B1 of tile1 ----
    STAGE_A(0, 0, 0); STAGE_A(0, 1, 0);
    STAGE_B(0, 0, 0); STAGE_B(0, 1, 0);
    STAGE_B(1, 0, 32768); STAGE_B(1, 1, 32768);
    asm volatile("s_waitcnt vmcnt(4)" ::: "memory");   // tile 0 landed
    __builtin_amdgcn_s_barrier();

    for (int t = 0; t < NT; ++t) {
        const int buf  = (t & 1) * 32768;
        const int bufo = buf ^ 32768;
        const int t1c  = (t + 1 < NT) ? (t + 1) : (NT - 1);
        const int t2c  = (t + 2 < NT) ? (t + 2) : (NT - 1);

        short8 aF[8], b01[2], b23[2], bk1[4];

        // ---------------- ph1: (kk0, n0-1) ----------------
#pragma unroll
        for (int m = 0; m < 8; ++m)
            aF[m] = *(const short8*)&lds[buf + aRow + m * 1024 + uk0];
        b01[0] = *(const short8*)&lds[buf + bRow + 0    + uk0];
        b01[1] = *(const short8*)&lds[buf + bRow + 1024 + uk0];
        STAGE_A(t1c, 0, bufo);
        __builtin_amdgcn_s_barrier();
        asm volatile("s_waitcnt lgkmcnt(0)" ::: "memory");
        __builtin_amdgcn_s_setprio(1);
#pragma unroll
        for (int m = 0; m < 8; ++m)
#pragma unroll
            for (int n = 0; n < 2; ++n)
                acc[m][n] = MFMA(aF[m], b01[n], acc[m][n]);
        __builtin_amdgcn_s_setprio(0);
        __builtin_amdgcn_s_barrier();

        // ---------------- ph2: (kk0, n2-3) ----------------
        b23[0] = *(const short8*)&lds[buf + bRow + 2048 + uk0];
        b23[1] = *(const short8*)&lds[buf + bRow + 3072 + uk0];
#pragma unroll
        for (int n = 0; n < 4; ++n)
            bk1[n] = *(const short8*)&lds[buf + bRow + n * 1024 + uk1];
        STAGE_A(t1c, 1, bufo);
        __builtin_amdgcn_s_barrier();
        asm volatile("s_waitcnt lgkmcnt(0)" ::: "memory");
        __builtin_amdgcn_s_setprio(1);
#pragma unroll
        for (int m = 0; m < 8; ++m)
#pragma unroll
            for (int n = 0; n < 2; ++n)
                acc[m][n + 2] = MFMA(aF[m], b23[n], acc[m][n + 2]);
        __builtin_amdgcn_s_setprio(0);
        __builtin_amdgcn_s_barrier();

        // ---------------- ph3: (kk1, n0-1) ----------------
#pragma unroll
        for (int m = 0; m < 8; ++m)
            aF[m] = *(const short8*)&lds[buf + aRow + m * 1024 + uk1];
        STAGE_B(t2c, 0, buf);
        __builtin_amdgcn_s_barrier();
        asm volatile("s_waitcnt lgkmcnt(0)" ::: "memory");
        __builtin_amdgcn_s_setprio(1);
#pragma unroll
        for (int m = 0; m < 8; ++m)
#pragma unroll
            for (int n = 0; n < 2; ++n)
                acc[m][n] = MFMA(aF[m], bk1[n], acc[m][n]);
        __builtin_amdgcn_s_setprio(0);
        __builtin_amdgcn_s_barrier();

        // ---------------- ph4: (kk1, n2-3) ----------------
        STAGE_B(t2c, 1, buf);
        asm volatile("s_waitcnt vmcnt(4)" ::: "memory");   // tile t+1 landed
        __builtin_amdgcn_s_barrier();
        __builtin_amdgcn_s_setprio(1);
#pragma unroll
        for (int m = 0; m < 8; ++m)
#pragma unroll
            for (int n = 0; n < 2; ++n)
                acc[m][n + 2] = MFMA(aF[m], bk1[n + 2], acc[m][n + 2]);
        __builtin_amdgcn_s_setprio(0);
        __builtin_amdgcn_s_barrier();
    }

    // epilogue: C/D layout col = lane&15, row = (lane>>4)*4 + reg
    const int r0 = rowBase + wr * 128 + l4 * 4;
    const int c0 = colBase + wc * 64 + l15;
#pragma unroll
    for (int m = 0; m < 8; ++m)
#pragma unroll
        for (int n = 0; n < 4; ++n) {
            float* cp = C + (size_t)(r0 + m * 16) * M_DIM + (c0 + n * 16);
#pragma unroll
            for (int reg = 0; reg < 4; ++reg)
                cp[(size_t)reg * M_DIM] = acc[m][n][reg];
        }
}

// ---------------------------------------------------------------------------
extern "C" void kernel_launch(void* const* d_in, const int* in_sizes, int n_in,
                              void* d_out, int out_size, void* d_ws, size_t ws_size,
                              hipStream_t stream) {
    const float* inp  = (const float*)d_in[0];
    const int*   qidx = (const int*)d_in[1];
    const float* cb   = (const float*)d_in[2];
    float* out = (float*)d_out;

    short* Wb = (short*)d_ws;
    short* Ab = Wb + (size_t)M_DIM * K_DIM;

    prep_kernel<<<16384, 256, 0, stream>>>(qidx, cb, Wb, inp, Ab);

    gemm_bt_kernel<<<256, 512, 0, stream>>>(Ab, Wb, out);
}